// Round 5
// baseline (447.690 us; speedup 1.0000x reference)
//
#include <hip/hip_runtime.h>

// GraphConvolution: out = segment_sum(edge_val * (x@W)[edge_col], edge_row) + b
// M=100000 nodes, K=256 in_feats, N=128 out_feats, E=1.6M edges. fp32 in/out.
//
// R8 (358.5us): split-wave spmm (8 gathers in flight/wave).
// R9 (329.3us): barrier-free gemm fused with edge partition (mod-5 roles).
// R10: (a) replace two-level bucket sort with direct CSR counting sort:
//      row-hist (fused into gemm dispatch, global atomics on 400KB L2-resident
//      counters, ~16/row so no chains) -> 2-kernel scan -> single scatter.
//      Deletes bucket_scan + bucket_to_sorted (a full extra edge pass).
//      (b) gemm A-conversion via v_cvt_pk_bf16_f32 (8 VALU/K-step vs 64 for
//      manual RNE f2bf -- conversion alone was > MFMA time).
//      (c) explicit prefetch-1 on x loads, issued after bfrag loads so the
//      bfrag vmcnt wait doesn't drain them.

#define K_FEATS 256
#define N_FEATS 128
#define CHUNK 8192
#define EPT 32                   // edges per thread (256 threads)
#define RMOD 5                   // 1 of every RMOD blocks is a hist block

typedef __attribute__((ext_vector_type(8))) short short8;
typedef __attribute__((ext_vector_type(4))) float float4v;

__device__ __forceinline__ unsigned short f2bf(float f) {
    unsigned int u = __float_as_uint(f);
    unsigned int r = u + 0x7FFF + ((u >> 16) & 1);   // round-to-nearest-even
    return (unsigned short)(r >> 16);
}

__device__ __forceinline__ unsigned int cvt_pk_bf16(float lo, float hi) {
    unsigned int r;
    asm("v_cvt_pk_bf16_f32 %0, %1, %2" : "=v"(r) : "v"(lo), "v"(hi));
    return r;
}

// ---------------- prep: Wt bf16 + zero row counters, one dispatch ----------
__global__ __launch_bounds__(256) void prep_zero(const float* __restrict__ w,
                                                 unsigned short* __restrict__ wt,
                                                 int* __restrict__ rcnt, int M) {
    int g = blockIdx.x;
    if (g < N_FEATS) {
        int k = threadIdx.x;
        wt[g * K_FEATS + k] = f2bf(w[k * N_FEATS + g]);
        return;
    }
    int i = (g - N_FEATS) * 256 + threadIdx.x;
    if (i < M) rcnt[i] = 0;
}

// ---------------- fused: barrier-free GEMM + row histogram ----------------
// blockIdx % RMOD == 0 -> hist chunk; else gemm tile (128 rows).
__global__ __launch_bounds__(256) void gemm_hist(
        const float* __restrict__ x, const unsigned short* __restrict__ wt,
        unsigned short* __restrict__ sup, int M, int NT,
        const int* __restrict__ erow, int* __restrict__ rcnt, int E, int NCH) {
    const int g   = blockIdx.x;
    const int tid = threadIdx.x;

    if (g % RMOD == 0) {
        // ---------- hist role: coalesced erow read, scattered atomics ----------
        int pid = g / RMOD;
        if (pid >= NCH) return;
        const long e0 = (long)pid * CHUNK;
#pragma unroll
        for (int i = 0; i < EPT; i++) {
            long e = e0 + tid + i * 256;
            if (e < E) atomicAdd(&rcnt[erow[e]], 1);
        }
        return;
    }

    // ---------- gemm role: barrier-free, per-wave-exclusive A ----------
    int tile = g - g / RMOD - 1;
    if (tile >= NT) return;

    const int wv   = tid >> 6;
    const int lane = tid & 63;
    const int l15  = lane & 15;
    const int quad = lane >> 4;
    const int row0 = tile * 128 + wv * 32;   // this wave's 32 rows

    float4v acc[2][8];
#pragma unroll
    for (int mt = 0; mt < 2; mt++)
#pragma unroll
        for (int nt = 0; nt < 8; nt++) acc[mt][nt] = (float4v)(0.f);

    // prologue: load k0=0 A-data
    float4 ca[2][2];
#pragma unroll
    for (int mt = 0; mt < 2; mt++) {
        int grow = row0 + mt * 16 + l15;
        ca[mt][0] = make_float4(0.f, 0.f, 0.f, 0.f);
        ca[mt][1] = make_float4(0.f, 0.f, 0.f, 0.f);
        if (grow < M) {
            const float* p = x + (long)grow * K_FEATS + quad * 8;
            ca[mt][0] = *(const float4*)p;
            ca[mt][1] = *(const float4*)(p + 4);
        }
    }

#pragma unroll 2
    for (int k0 = 0; k0 < K_FEATS; k0 += 32) {
        // bfrag loads first: the MFMA's vmcnt wait targets these...
        short8 bfrag[8];
#pragma unroll
        for (int nt = 0; nt < 8; nt++) {
            bfrag[nt] = *(const short8*)(wt + (nt * 16 + l15) * K_FEATS + k0 + quad * 8);
        }
        // ...then prefetch next K-step's A (stays in flight across the MFMAs)
        float4 na[2][2];
        if (k0 + 32 < K_FEATS) {
#pragma unroll
            for (int mt = 0; mt < 2; mt++) {
                int grow = row0 + mt * 16 + l15;
                na[mt][0] = make_float4(0.f, 0.f, 0.f, 0.f);
                na[mt][1] = make_float4(0.f, 0.f, 0.f, 0.f);
                if (grow < M) {
                    const float* p = x + (long)grow * K_FEATS + (k0 + 32) + quad * 8;
                    na[mt][0] = *(const float4*)p;
                    na[mt][1] = *(const float4*)(p + 4);
                }
            }
        }
        // pack current A to bf16: 8 x v_cvt_pk_bf16_f32 (vs 64 VALU for manual RNE)
        short8 afrag[2];
#pragma unroll
        for (int mt = 0; mt < 2; mt++) {
            union { short8 s; uint4 u; } cv;
            cv.u.x = cvt_pk_bf16(ca[mt][0].x, ca[mt][0].y);
            cv.u.y = cvt_pk_bf16(ca[mt][0].z, ca[mt][0].w);
            cv.u.z = cvt_pk_bf16(ca[mt][1].x, ca[mt][1].y);
            cv.u.w = cvt_pk_bf16(ca[mt][1].z, ca[mt][1].w);
            afrag[mt] = cv.s;
        }
#pragma unroll
        for (int mt = 0; mt < 2; mt++)
#pragma unroll
            for (int nt = 0; nt < 8; nt++)
                acc[mt][nt] = __builtin_amdgcn_mfma_f32_16x16x32_bf16(
                    afrag[mt], bfrag[nt], acc[mt][nt], 0, 0, 0);
#pragma unroll
        for (int mt = 0; mt < 2; mt++) {
            ca[mt][0] = na[mt][0];
            ca[mt][1] = na[mt][1];
        }
    }

#pragma unroll
    for (int mt = 0; mt < 2; mt++) {
#pragma unroll
        for (int reg = 0; reg < 4; reg++) {
            int grow = row0 + mt * 16 + quad * 4 + reg;
            if (grow < M) {
#pragma unroll
                for (int nt = 0; nt < 8; nt++) {
                    sup[(long)grow * N_FEATS + nt * 16 + l15] = f2bf(acc[mt][nt][reg]);
                }
            }
        }
    }
}

// ---------------- CSR scan: 1024 elements per block ----------------
__global__ __launch_bounds__(256) void scan_partial(const int* __restrict__ rcnt,
                                                    int* __restrict__ bsum, int M) {
    __shared__ int sm[256];
    const int blk = blockIdx.x, t = threadIdx.x;
    const int base = blk * 1024 + t * 4;
    int s = 0;
#pragma unroll
    for (int j = 0; j < 4; j++) {
        int i = base + j;
        if (i < M) s += rcnt[i];
    }
    sm[t] = s;
    __syncthreads();
    for (int st = 128; st > 0; st >>= 1) {
        if (t < st) sm[t] += sm[t + st];
        __syncthreads();
    }
    if (t == 0) bsum[blk] = sm[0];
}

// each block re-scans the (<=128) partials locally, then scans its 1024 counts
// -> off0 (exclusive) and cur (scatter cursors); off0[M] = E total.
__global__ __launch_bounds__(256) void scan_final(const int* __restrict__ rcnt,
                                                  const int* __restrict__ bsum,
                                                  int* __restrict__ off0,
                                                  int* __restrict__ cur, int M, int NB1) {
    __shared__ int pb[128];
    __shared__ int sm[256];
    const int blk = blockIdx.x, t = threadIdx.x;

    if (t < 128) pb[t] = (t < NB1) ? bsum[t] : 0;
    __syncthreads();
    for (int st = 1; st < 128; st <<= 1) {
        int v = 0;
        if (t >= st && t < 128) v = pb[t - st];
        __syncthreads();
        if (t < 128) pb[t] += v;
        __syncthreads();
    }
    const int blockBase = (blk == 0) ? 0 : pb[blk - 1];

    const int base = blk * 1024 + t * 4;
    int v[4];
    int s = 0;
#pragma unroll
    for (int j = 0; j < 4; j++) {
        int i = base + j;
        v[j] = (i < M) ? rcnt[i] : 0;
        s += v[j];
    }
    sm[t] = s;
    __syncthreads();
    for (int st = 1; st < 256; st <<= 1) {
        int a = 0;
        if (t >= st) a = sm[t - st];
        __syncthreads();
        sm[t] += a;
        __syncthreads();
    }
    int tb = blockBase + ((t == 0) ? 0 : sm[t - 1]);
#pragma unroll
    for (int j = 0; j < 4; j++) {
        int i = base + j;
        if (i < M) {
            off0[i] = tb;
            cur[i]  = tb;
            tb += v[j];
            if (i == M - 1) off0[M] = tb;
        }
    }
}

// ---------------- scatter: edges -> row-grouped sedge via cursor atomics ----
__global__ __launch_bounds__(256) void csr_scatter(const int* __restrict__ erow,
                                                   const int* __restrict__ ecol,
                                                   const float* __restrict__ eval_,
                                                   int* __restrict__ cur,
                                                   int2* __restrict__ sedge, int E) {
    const int gid = blockIdx.x * 256 + threadIdx.x;
    const int T   = gridDim.x * 256;
    for (int e = gid; e < E; e += T) {
        int r = erow[e];
        int p = atomicAdd(&cur[r], 1);
        sedge[p] = make_int2(ecol[e], __float_as_int(eval_[e]));
    }
}

// ---------------- SpMM: wave per row, split-wave edge pairs, no atomics ------
// Two 32-lane halves; each lane = 4 feats (uint2 = 4 bf16); half h processes
// edges at offset s+h, s+h+2, ... Unroll 4 -> 8 gathers in flight per wave.
__global__ __launch_bounds__(256) void gcn_spmm(const int* __restrict__ off0,
                                                const int2* __restrict__ sedge,
                                                const unsigned short* __restrict__ sup,
                                                const float* __restrict__ b,
                                                float* __restrict__ out, int M) {
    int row  = blockIdx.x * 4 + (threadIdx.x >> 6);
    if (row >= M) return;
    int lane = threadIdx.x & 63;
    int half = lane >> 5;
    int l31  = lane & 31;
    int s = off0[row], e = off0[row + 1];
    const uint2* sup64 = (const uint2*)sup;   // 4 bf16 per uint2

    float4v acc = (float4v)(0.f);
    int base = s;
    for (; base + 8 <= e; base += 8) {
        int2 ed[4];
#pragma unroll
        for (int u = 0; u < 4; u++) ed[u] = sedge[base + half + 2 * u];
        uint2 g[4];
#pragma unroll
        for (int u = 0; u < 4; u++) g[u] = sup64[(long)ed[u].x * 32 + l31];
#pragma unroll
        for (int u = 0; u < 4; u++) {
            float v = __int_as_float(ed[u].y);
            acc.x += v * __uint_as_float(g[u].x << 16);
            acc.y += v * __uint_as_float(g[u].x & 0xFFFF0000u);
            acc.z += v * __uint_as_float(g[u].y << 16);
            acc.w += v * __uint_as_float(g[u].y & 0xFFFF0000u);
        }
    }
    for (int i = base + half; i < e; i += 2) {
        int2 ed = sedge[i];
        uint2 g = sup64[(long)ed.x * 32 + l31];
        float v = __int_as_float(ed.y);
        acc.x += v * __uint_as_float(g.x << 16);
        acc.y += v * __uint_as_float(g.x & 0xFFFF0000u);
        acc.z += v * __uint_as_float(g.y << 16);
        acc.w += v * __uint_as_float(g.y & 0xFFFF0000u);
    }

    // cross-half reduce: half 1's partials fold into half 0
    acc.x += __shfl_xor(acc.x, 32);
    acc.y += __shfl_xor(acc.y, 32);
    acc.z += __shfl_xor(acc.z, 32);
    acc.w += __shfl_xor(acc.w, 32);

    if (half == 0) {
        float4v bb = ((const float4v*)b)[l31];
        acc += bb;
        *(float4v*)(out + (long)row * N_FEATS + l31 * 4) = acc;
    }
}

extern "C" void kernel_launch(void* const* d_in, const int* in_sizes, int n_in,
                              void* d_out, int out_size, void* d_ws, size_t ws_size,
                              hipStream_t stream) {
    const float* x     = (const float*)d_in[0];
    const int*   erow  = (const int*)d_in[1];
    const int*   ecol  = (const int*)d_in[2];
    const float* eval_ = (const float*)d_in[3];
    const float* w     = (const float*)d_in[4];
    const float* b     = (const float*)d_in[5];
    float* out = (float*)d_out;

    const int M   = in_sizes[0] / K_FEATS;     // 100000
    const int E   = in_sizes[1];               // 1600000
    const int NT  = (M + 127) / 128;           // 782 gemm tiles
    const int NCH = (E + CHUNK - 1) / CHUNK;   // 196 hist chunks
    const int NB1 = (M + 1023) / 1024;         // 98 scan blocks

    // workspace layout (16B aligned)
    size_t o_sup  = 0;                                               // bf16 sup
    size_t o_wt   = o_sup  + (((size_t)M * N_FEATS * 2 + 15) & ~15ul);
    size_t o_off0 = o_wt   + (size_t)K_FEATS * N_FEATS * 2;
    size_t o_rcnt = o_off0 + (((size_t)(M + 1) * 4 + 15) & ~15ul);
    size_t o_cur  = o_rcnt + (((size_t)M * 4 + 15) & ~15ul);
    size_t o_bsum = o_cur  + (((size_t)M * 4 + 15) & ~15ul);
    size_t o_edge = o_bsum + (((size_t)NB1 * 4 + 15) & ~15ul);

    unsigned short* sup  = (unsigned short*)((char*)d_ws + o_sup);
    unsigned short* wt   = (unsigned short*)((char*)d_ws + o_wt);
    int*            off0 = (int*)((char*)d_ws + o_off0);
    int*            rcnt = (int*)((char*)d_ws + o_rcnt);
    int*            cur  = (int*)((char*)d_ws + o_cur);
    int*            bsum = (int*)((char*)d_ws + o_bsum);
    int2*           sedge = (int2*)((char*)d_ws + o_edge);

    // Wt bf16 + rcnt=0 in one dispatch
    prep_zero<<<N_FEATS + (M + 255) / 256, 256, 0, stream>>>(w, wt, rcnt, M);

    // fused dense GEMM + row histogram (independent until scan)
    gemm_hist<<<NT + NCH, 256, 0, stream>>>(x, wt, sup, M, NT, erow, rcnt, E, NCH);

    // CSR offsets
    scan_partial<<<NB1, 256, 0, stream>>>(rcnt, bsum, M);
    scan_final<<<NB1, 256, 0, stream>>>(rcnt, bsum, off0, cur, M, NB1);

    // edges -> row-grouped sedge
    csr_scatter<<<(E + 2047) / 2048, 256, 0, stream>>>(erow, ecol, eval_, cur, sedge, E);

    // out[row] = sum(val * sup[col]) + b
    gcn_spmm<<<(M + 3) / 4, 256, 0, stream>>>(off0, sedge, sup, b, out, M);
}

// Round 6
// 317.539 us; speedup vs baseline: 1.4099x; 1.4099x over previous
//
#include <hip/hip_runtime.h>

// GraphConvolution: out = segment_sum(edge_val * (x@W)[edge_col], edge_row) + b
// M=100000 nodes, K=256 in_feats, N=128 out_feats, E=1.6M edges. fp32 in/out.
//
// R8 (358.5us): split-wave spmm (8 gathers in flight/wave).
// R9 (329.3us): barrier-free gemm fused with edge partition (mod-5 roles).
// R10 FAILED (447.7us): global CSR scatter = 100MB amplified writes (8B
// scattered stores -> 64B granules) + dependent atomic chains. Reverted.
// R11: never materialize sorted edges in global. Merge scan+sort+spmm into
// ONE kernel: block per 128-row bucket loads its tmp edges once into a
// register stash, LDS int-hist + scan (proven fast), places edges into a
// 24KB LDS sorted array, then each wave runs the R8 split-wave gather loop
// over its 32 rows reading edge records from LDS (broadcast ds_read_b64),
// storing out coalesced. Kills sedge global round-trip + 2 launches.

#define K_FEATS 256
#define N_FEATS 128
#define BSHIFT 7                 // 128 rows per bucket
#define BROWS 128
#define BCAP 3072                // mean 2048, +22 sigma
#define STASH 12                 // BCAP / 256
#define CHUNK 8192
#define EPT 32                   // edges per thread (256 threads)
#define RMOD 5                   // 1 of every RMOD blocks is a partition block

typedef __attribute__((ext_vector_type(8))) short short8;
typedef __attribute__((ext_vector_type(4))) float float4v;

__device__ __forceinline__ unsigned short f2bf(float f) {
    unsigned int u = __float_as_uint(f);
    unsigned int r = u + 0x7FFF + ((u >> 16) & 1);   // round-to-nearest-even
    return (unsigned short)(r >> 16);
}

// ---------------- prep: Wt[n][k] bf16 from w[k][n] fp32 ----------------
__global__ __launch_bounds__(256) void prep_w(const float* __restrict__ w,
                                              unsigned short* __restrict__ wt) {
    int n = blockIdx.x;
    int k = threadIdx.x;
    wt[n * K_FEATS + k] = f2bf(w[k * N_FEATS + n]);
}

__global__ __launch_bounds__(256) void zero_ints(int* __restrict__ p, int n) {
    int i = blockIdx.x * 256 + threadIdx.x;
    if (i < n) p[i] = 0;
}

// ---------------- fused: barrier-free GEMM + edge partition ----------------
// blockIdx % RMOD == 0 -> partition chunk; else gemm tile (128 rows).
__global__ __launch_bounds__(256) void gemm_partition(
        const float* __restrict__ x, const unsigned short* __restrict__ wt,
        unsigned short* __restrict__ sup, int M, int NT,
        const int* __restrict__ erow, const int* __restrict__ ecol,
        const float* __restrict__ eval_, int* __restrict__ bcur,
        int2* __restrict__ tmp, int E, int NB, int NCH) {
    __shared__ int hist[1024];
    __shared__ int cur[1024];
    const int g   = blockIdx.x;
    const int tid = threadIdx.x;

    if (g % RMOD == 0) {
        // ---------- partition role ----------
        int pid = g / RMOD;
        if (pid >= NCH) return;
        const long e0 = (long)pid * CHUNK;

        for (int i = tid; i < NB; i += 256) hist[i] = 0;
        __syncthreads();

        int rows[EPT];
#pragma unroll
        for (int i = 0; i < EPT; i++) {
            long e = e0 + tid + i * 256;
            int r = -1;
            if (e < E) {
                r = erow[e];
                atomicAdd(&hist[r >> BSHIFT], 1);
            }
            rows[i] = r;
        }
        __syncthreads();

        // one global reservation per touched bucket
        for (int i = tid; i < NB; i += 256) {
            int c = hist[i];
            cur[i] = c ? atomicAdd(&bcur[i], c) : 0;
        }
        __syncthreads();

        // place edges: LDS cursor gives offset within this WG's reserved run
#pragma unroll
        for (int i = 0; i < EPT; i++) {
            long e = e0 + tid + i * 256;
            if (e >= E) continue;
            int r = rows[i];
            int b = r >> BSHIFT;
            int p = atomicAdd(&cur[b], 1);
            if (p < BCAP)
                tmp[(long)b * BCAP + p] = make_int2(((r & (BROWS - 1)) << 17) | ecol[e],
                                                    __float_as_int(eval_[e]));
        }
        return;
    }

    // ---------- gemm role: barrier-free, per-wave-exclusive A ----------
    int tile = g - g / RMOD - 1;
    if (tile >= NT) return;

    const int wv   = tid >> 6;
    const int lane = tid & 63;
    const int l15  = lane & 15;
    const int quad = lane >> 4;
    const int row0 = tile * 128 + wv * 32;   // this wave's 32 rows

    float4v acc[2][8];
#pragma unroll
    for (int mt = 0; mt < 2; mt++)
#pragma unroll
        for (int nt = 0; nt < 8; nt++) acc[mt][nt] = (float4v)(0.f);

#pragma unroll 2
    for (int k0 = 0; k0 < K_FEATS; k0 += 32) {
        short8 afrag[2];
#pragma unroll
        for (int mt = 0; mt < 2; mt++) {
            int grow = row0 + mt * 16 + l15;
            float4 a0 = make_float4(0.f, 0.f, 0.f, 0.f);
            float4 a1 = make_float4(0.f, 0.f, 0.f, 0.f);
            if (grow < M) {
                const float* p = x + (long)grow * K_FEATS + k0 + quad * 8;
                a0 = *(const float4*)p;
                a1 = *(const float4*)(p + 4);
            }
            short8 af;
            af[0] = (short)f2bf(a0.x); af[1] = (short)f2bf(a0.y);
            af[2] = (short)f2bf(a0.z); af[3] = (short)f2bf(a0.w);
            af[4] = (short)f2bf(a1.x); af[5] = (short)f2bf(a1.y);
            af[6] = (short)f2bf(a1.z); af[7] = (short)f2bf(a1.w);
            afrag[mt] = af;
        }
        short8 bfrag[8];
#pragma unroll
        for (int nt = 0; nt < 8; nt++) {
            bfrag[nt] = *(const short8*)(wt + (nt * 16 + l15) * K_FEATS + k0 + quad * 8);
        }
#pragma unroll
        for (int mt = 0; mt < 2; mt++)
#pragma unroll
            for (int nt = 0; nt < 8; nt++)
                acc[mt][nt] = __builtin_amdgcn_mfma_f32_16x16x32_bf16(
                    afrag[mt], bfrag[nt], acc[mt][nt], 0, 0, 0);
    }

#pragma unroll
    for (int mt = 0; mt < 2; mt++) {
#pragma unroll
        for (int reg = 0; reg < 4; reg++) {
            int grow = row0 + mt * 16 + quad * 4 + reg;
            if (grow < M) {
#pragma unroll
                for (int nt = 0; nt < 8; nt++) {
                    sup[(long)grow * N_FEATS + nt * 16 + l15] = f2bf(acc[mt][nt][reg]);
                }
            }
        }
    }
}

// ---------------- fused sort+spmm: block per bucket, sort in LDS -----------
// Phase A: tmp edges -> register stash + LDS hist; 128-scan; place into
// LDS sorted array (no global scatter). Phase B: wave per 32 rows, R8
// split-wave gather loop reading edge records from LDS.
__global__ __launch_bounds__(256) void bucket_spmm(const int* __restrict__ bcnt,
                                                   const int2* __restrict__ tmp,
                                                   const unsigned short* __restrict__ sup,
                                                   const float* __restrict__ b,
                                                   float* __restrict__ out, int M) {
    __shared__ int hist[BROWS];
    __shared__ int rs[BROWS];
    __shared__ int cur[BROWS];
    __shared__ __align__(16) int2 se[BCAP];      // 24 KB
    const int bkt  = blockIdx.x;
    const int tid  = threadIdx.x;
    const int wv   = tid >> 6;
    const int lane = tid & 63;
    const int row0 = bkt << BSHIFT;

    if (tid < BROWS) hist[tid] = 0;
    __syncthreads();

    int cnt = bcnt[bkt];
    if (cnt > BCAP) cnt = BCAP;
    const int2* t = tmp + (long)bkt * BCAP;

    // Phase A1: single global read of bucket edges -> stash + histogram
    int2 stash[STASH];
#pragma unroll
    for (int j = 0; j < STASH; j++) {
        int i = tid + j * 256;
        if (i < cnt) {
            int2 e = t[i];
            stash[j] = e;
            atomicAdd(&hist[(unsigned)e.x >> 17], 1);
        }
    }
    __syncthreads();

    // Phase A2: exclusive scan of 128 row counts
    if (tid < BROWS) cur[tid] = hist[tid];
    __syncthreads();
#pragma unroll
    for (int s = 1; s < BROWS; s <<= 1) {
        int v = 0;
        if (tid >= s && tid < BROWS) v = cur[tid - s];
        __syncthreads();
        if (tid < BROWS) cur[tid] += v;
        __syncthreads();
    }
    if (tid < BROWS) {
        int start = cur[tid] - hist[tid];        // exclusive
        rs[tid]  = start;
        cur[tid] = start;
    }
    __syncthreads();

    // Phase A3: place edges into LDS sorted array (col stripped of row bits)
#pragma unroll
    for (int j = 0; j < STASH; j++) {
        int i = tid + j * 256;
        if (i < cnt) {
            int2 e = stash[j];
            int rl = (unsigned)e.x >> 17;
            int p = atomicAdd(&cur[rl], 1);
            se[p] = make_int2(e.x & 0x1FFFF, e.y);
        }
    }
    __syncthreads();

    // Phase B: wave per 32 rows, split-wave gather (8 in flight)
    const int half = lane >> 5;
    const int l31  = lane & 31;
    const uint2* sup64 = (const uint2*)sup;      // 4 bf16 per uint2
    const float4v bb = ((const float4v*)b)[l31];

    for (int rr = 0; rr < 32; rr++) {
        int r    = wv * 32 + rr;
        int grow = row0 + r;
        if (grow >= M) break;                    // only trims the last bucket
        int s  = rs[r];
        int e2 = s + hist[r];

        float4v acc = (float4v)(0.f);
        int base = s;
        for (; base + 8 <= e2; base += 8) {
            int2 ed[4];
#pragma unroll
            for (int u = 0; u < 4; u++) ed[u] = se[base + half + 2 * u];
            uint2 g[4];
#pragma unroll
            for (int u = 0; u < 4; u++) g[u] = sup64[(long)ed[u].x * 32 + l31];
#pragma unroll
            for (int u = 0; u < 4; u++) {
                float v = __int_as_float(ed[u].y);
                acc.x += v * __uint_as_float(g[u].x << 16);
                acc.y += v * __uint_as_float(g[u].x & 0xFFFF0000u);
                acc.z += v * __uint_as_float(g[u].y << 16);
                acc.w += v * __uint_as_float(g[u].y & 0xFFFF0000u);
            }
        }
        for (int i = base + half; i < e2; i += 2) {
            int2 ed = se[i];
            uint2 g = sup64[(long)ed.x * 32 + l31];
            float v = __int_as_float(ed.y);
            acc.x += v * __uint_as_float(g.x << 16);
            acc.y += v * __uint_as_float(g.x & 0xFFFF0000u);
            acc.z += v * __uint_as_float(g.y << 16);
            acc.w += v * __uint_as_float(g.y & 0xFFFF0000u);
        }

        // cross-half reduce: half 1's partials fold into half 0
        acc.x += __shfl_xor(acc.x, 32);
        acc.y += __shfl_xor(acc.y, 32);
        acc.z += __shfl_xor(acc.z, 32);
        acc.w += __shfl_xor(acc.w, 32);

        if (half == 0) {
            float4v o = acc + bb;
            *(float4v*)(out + (long)grow * N_FEATS + l31 * 4) = o;
        }
    }
}

extern "C" void kernel_launch(void* const* d_in, const int* in_sizes, int n_in,
                              void* d_out, int out_size, void* d_ws, size_t ws_size,
                              hipStream_t stream) {
    const float* x     = (const float*)d_in[0];
    const int*   erow  = (const int*)d_in[1];
    const int*   ecol  = (const int*)d_in[2];
    const float* eval_ = (const float*)d_in[3];
    const float* w     = (const float*)d_in[4];
    const float* b     = (const float*)d_in[5];
    float* out = (float*)d_out;

    const int M   = in_sizes[0] / K_FEATS;     // 100000
    const int E   = in_sizes[1];               // 1600000
    const int NB  = (M + BROWS - 1) >> BSHIFT; // 782
    const int NT  = (M + 127) / 128;           // 782 gemm tiles
    const int NCH = (E + CHUNK - 1) / CHUNK;   // 196 partition chunks

    // workspace layout (16B aligned)
    size_t o_sup  = 0;                                               // bf16 sup
    size_t o_wt   = o_sup  + (((size_t)M * N_FEATS * 2 + 15) & ~15ul);
    size_t o_bcur = o_wt   + (size_t)K_FEATS * N_FEATS * 2;
    size_t o_tmp  = o_bcur + (((size_t)NB * 4 + 15) & ~15ul);

    unsigned short* sup  = (unsigned short*)((char*)d_ws + o_sup);
    unsigned short* wt   = (unsigned short*)((char*)d_ws + o_wt);
    int*            bcur = (int*)((char*)d_ws + o_bcur);
    int2*           tmp  = (int2*)((char*)d_ws + o_tmp);

    prep_w<<<N_FEATS, 256, 0, stream>>>(w, wt);
    zero_ints<<<(NB + 255) / 256, 256, 0, stream>>>(bcur, NB);

    // fused dense GEMM + sparse partition (independent until bucket_spmm)
    gemm_partition<<<NT + NCH, 256, 0, stream>>>(x, wt, sup, M, NT,
                                                 erow, ecol, eval_, bcur, tmp, E, NB, NCH);

    // sort-in-LDS + gather + out, one kernel, no global sedge
    bucket_spmm<<<NB, 256, 0, stream>>>(bcur, tmp, sup, b, out, M);
}

// Round 7
// 312.836 us; speedup vs baseline: 1.4311x; 1.0150x over previous
//
#include <hip/hip_runtime.h>

// GraphConvolution: out = segment_sum(edge_val * (x@W)[edge_col], edge_row) + b
// M=100000 nodes, K=256 in_feats, N=128 out_feats, E=1.6M edges. fp32 in/out.
//
// R8 (358.5us): split-wave spmm (8 gathers in flight/wave).
// R9 (329.3us): barrier-free gemm fused with edge partition (mod-5 roles).
// R10 FAILED (447.7us): global CSR scatter = 100MB amplified 8B writes.
// R11 (317.5us): sort-in-LDS bucket_spmm (no global sedge), one kernel.
// R12: (a) gemm A-load software pipeline: issue k+1's 4xfloat4 before k's
//      MFMAs (branchless (k0+32)&255 wrap) -- kills the per-K-step
//      load->f2bf->MFMA stall that kept the kernel at 12.6% HBM / 2% MFMA.
//      (b) 64-row buckets (BSHIFT 6): bucket_spmm LDS 25KB->15KB, grid
//      782->1563 blocks => ~6 blocks/CU (~24 waves) vs ~3 -- double the
//      latency hiding on the gather loop (kept identical to proven R8).

#define K_FEATS 256
#define N_FEATS 128
#define BSHIFT 6                 // 64 rows per bucket
#define BROWS 64
#define BCAP 1792                // mean 1024, sigma 32 -> +24 sigma
#define STASH 7                  // BCAP / 256
#define NBPAD 2048               // partition LDS hist capacity (NB = 1563)
#define CHUNK 8192
#define EPT 32                   // edges per thread (256 threads)
#define RMOD 5                   // 1 of every RMOD blocks is a partition block

typedef __attribute__((ext_vector_type(8))) short short8;
typedef __attribute__((ext_vector_type(4))) float float4v;

__device__ __forceinline__ unsigned short f2bf(float f) {
    unsigned int u = __float_as_uint(f);
    unsigned int r = u + 0x7FFF + ((u >> 16) & 1);   // round-to-nearest-even
    return (unsigned short)(r >> 16);
}

// ---------------- prep: Wt[n][k] bf16 from w[k][n] fp32 ----------------
__global__ __launch_bounds__(256) void prep_w(const float* __restrict__ w,
                                              unsigned short* __restrict__ wt) {
    int n = blockIdx.x;
    int k = threadIdx.x;
    wt[n * K_FEATS + k] = f2bf(w[k * N_FEATS + n]);
}

__global__ __launch_bounds__(256) void zero_ints(int* __restrict__ p, int n) {
    int i = blockIdx.x * 256 + threadIdx.x;
    if (i < n) p[i] = 0;
}

// ---------------- fused: pipelined barrier-free GEMM + edge partition -------
// blockIdx % RMOD == 0 -> partition chunk; else gemm tile (128 rows).
__global__ __launch_bounds__(256) void gemm_partition(
        const float* __restrict__ x, const unsigned short* __restrict__ wt,
        unsigned short* __restrict__ sup, int M, int NT,
        const int* __restrict__ erow, const int* __restrict__ ecol,
        const float* __restrict__ eval_, int* __restrict__ bcur,
        int2* __restrict__ tmp, int E, int NB, int NCH) {
    __shared__ int hist[NBPAD];
    __shared__ int cur[NBPAD];
    const int g   = blockIdx.x;
    const int tid = threadIdx.x;

    if (g % RMOD == 0) {
        // ---------- partition role ----------
        int pid = g / RMOD;
        if (pid >= NCH) return;
        const long e0 = (long)pid * CHUNK;

        for (int i = tid; i < NB; i += 256) hist[i] = 0;
        __syncthreads();

        int rows[EPT];
#pragma unroll
        for (int i = 0; i < EPT; i++) {
            long e = e0 + tid + i * 256;
            int r = -1;
            if (e < E) {
                r = erow[e];
                atomicAdd(&hist[r >> BSHIFT], 1);
            }
            rows[i] = r;
        }
        __syncthreads();

        // one global reservation per touched bucket
        for (int i = tid; i < NB; i += 256) {
            int c = hist[i];
            cur[i] = c ? atomicAdd(&bcur[i], c) : 0;
        }
        __syncthreads();

        // place edges: LDS cursor gives offset within this WG's reserved run
#pragma unroll
        for (int i = 0; i < EPT; i++) {
            long e = e0 + tid + i * 256;
            if (e >= E) continue;
            int r = rows[i];
            int b = r >> BSHIFT;
            int p = atomicAdd(&cur[b], 1);
            if (p < BCAP)
                tmp[(long)b * BCAP + p] = make_int2(((r & (BROWS - 1)) << 17) | ecol[e],
                                                    __float_as_int(eval_[e]));
        }
        return;
    }

    // ---------- gemm role: barrier-free, per-wave-exclusive A, prefetch-1 ----
    int tile = g - g / RMOD - 1;
    if (tile >= NT) return;

    const int wv   = tid >> 6;
    const int lane = tid & 63;
    const int l15  = lane & 15;
    const int quad = lane >> 4;
    const int row0 = tile * 128 + wv * 32;   // this wave's 32 rows
    const int grow0 = row0 + l15;
    const int grow1 = row0 + 16 + l15;
    const bool ok0 = grow0 < M;
    const bool ok1 = grow1 < M;
    const float* p0 = x + (long)grow0 * K_FEATS + quad * 8;
    const float* p1 = x + (long)grow1 * K_FEATS + quad * 8;

    float4v acc[2][8];
#pragma unroll
    for (int mt = 0; mt < 2; mt++)
#pragma unroll
        for (int nt = 0; nt < 8; nt++) acc[mt][nt] = (float4v)(0.f);

    // prologue: A-data for k0 = 0
    float4 ca[2][2];
    ca[0][0] = ok0 ? *(const float4*)p0 : make_float4(0.f, 0.f, 0.f, 0.f);
    ca[0][1] = ok0 ? *(const float4*)(p0 + 4) : make_float4(0.f, 0.f, 0.f, 0.f);
    ca[1][0] = ok1 ? *(const float4*)p1 : make_float4(0.f, 0.f, 0.f, 0.f);
    ca[1][1] = ok1 ? *(const float4*)(p1 + 4) : make_float4(0.f, 0.f, 0.f, 0.f);

#pragma unroll
    for (int k0 = 0; k0 < K_FEATS; k0 += 32) {
        // prefetch next K-step's A first (wraps to 0 on last iter, L1-hot, unused)
        const int kn = (k0 + 32) & (K_FEATS - 1);
        float4 na[2][2];
        na[0][0] = ok0 ? *(const float4*)(p0 + kn) : make_float4(0.f, 0.f, 0.f, 0.f);
        na[0][1] = ok0 ? *(const float4*)(p0 + kn + 4) : make_float4(0.f, 0.f, 0.f, 0.f);
        na[1][0] = ok1 ? *(const float4*)(p1 + kn) : make_float4(0.f, 0.f, 0.f, 0.f);
        na[1][1] = ok1 ? *(const float4*)(p1 + kn + 4) : make_float4(0.f, 0.f, 0.f, 0.f);

        short8 bfrag[8];
#pragma unroll
        for (int nt = 0; nt < 8; nt++) {
            bfrag[nt] = *(const short8*)(wt + (nt * 16 + l15) * K_FEATS + k0 + quad * 8);
        }
        short8 afrag[2];
#pragma unroll
        for (int mt = 0; mt < 2; mt++) {
            short8 af;
            af[0] = (short)f2bf(ca[mt][0].x); af[1] = (short)f2bf(ca[mt][0].y);
            af[2] = (short)f2bf(ca[mt][0].z); af[3] = (short)f2bf(ca[mt][0].w);
            af[4] = (short)f2bf(ca[mt][1].x); af[5] = (short)f2bf(ca[mt][1].y);
            af[6] = (short)f2bf(ca[mt][1].z); af[7] = (short)f2bf(ca[mt][1].w);
            afrag[mt] = af;
        }
#pragma unroll
        for (int mt = 0; mt < 2; mt++)
#pragma unroll
            for (int nt = 0; nt < 8; nt++)
                acc[mt][nt] = __builtin_amdgcn_mfma_f32_16x16x32_bf16(
                    afrag[mt], bfrag[nt], acc[mt][nt], 0, 0, 0);
#pragma unroll
        for (int mt = 0; mt < 2; mt++) {
            ca[mt][0] = na[mt][0];
            ca[mt][1] = na[mt][1];
        }
    }

#pragma unroll
    for (int mt = 0; mt < 2; mt++) {
#pragma unroll
        for (int reg = 0; reg < 4; reg++) {
            int grow = row0 + mt * 16 + quad * 4 + reg;
            if (grow < M) {
#pragma unroll
                for (int nt = 0; nt < 8; nt++) {
                    sup[(long)grow * N_FEATS + nt * 16 + l15] = f2bf(acc[mt][nt][reg]);
                }
            }
        }
    }
}

// ---------------- fused sort+spmm: block per 64-row bucket ------------------
// Phase A: tmp edges -> register stash + LDS hist; 64-scan; place into LDS
// sorted array. Phase B: wave per 16 rows, R8 split-wave gather loop.
__global__ __launch_bounds__(256) void bucket_spmm(const int* __restrict__ bcnt,
                                                   const int2* __restrict__ tmp,
                                                   const unsigned short* __restrict__ sup,
                                                   const float* __restrict__ b,
                                                   float* __restrict__ out, int M) {
    __shared__ int hist[BROWS];
    __shared__ int rs[BROWS];
    __shared__ int cur[BROWS];
    __shared__ __align__(16) int2 se[BCAP];      // 14 KB
    const int bkt  = blockIdx.x;
    const int tid  = threadIdx.x;
    const int wv   = tid >> 6;
    const int lane = tid & 63;
    const int row0 = bkt << BSHIFT;

    if (tid < BROWS) hist[tid] = 0;
    __syncthreads();

    int cnt = bcnt[bkt];
    if (cnt > BCAP) cnt = BCAP;
    const int2* t = tmp + (long)bkt * BCAP;

    // Phase A1: single global read of bucket edges -> stash + histogram
    int2 stash[STASH];
#pragma unroll
    for (int j = 0; j < STASH; j++) {
        int i = tid + j * 256;
        if (i < cnt) {
            int2 e = t[i];
            stash[j] = e;
            atomicAdd(&hist[(unsigned)e.x >> 17], 1);
        }
    }
    __syncthreads();

    // Phase A2: exclusive scan of 64 row counts
    if (tid < BROWS) cur[tid] = hist[tid];
    __syncthreads();
#pragma unroll
    for (int s = 1; s < BROWS; s <<= 1) {
        int v = 0;
        if (tid >= s && tid < BROWS) v = cur[tid - s];
        __syncthreads();
        if (tid < BROWS) cur[tid] += v;
        __syncthreads();
    }
    if (tid < BROWS) {
        int start = cur[tid] - hist[tid];        // exclusive
        rs[tid]  = start;
        cur[tid] = start;
    }
    __syncthreads();

    // Phase A3: place edges into LDS sorted array (col stripped of row bits)
#pragma unroll
    for (int j = 0; j < STASH; j++) {
        int i = tid + j * 256;
        if (i < cnt) {
            int2 e = stash[j];
            int rl = (unsigned)e.x >> 17;
            int p = atomicAdd(&cur[rl], 1);
            se[p] = make_int2(e.x & 0x1FFFF, e.y);
        }
    }
    __syncthreads();

    // Phase B: wave per 16 rows, split-wave gather (8 in flight)
    const int half = lane >> 5;
    const int l31  = lane & 31;
    const uint2* sup64 = (const uint2*)sup;      // 4 bf16 per uint2
    const float4v bb = ((const float4v*)b)[l31];

    for (int rr = 0; rr < 16; rr++) {
        int r    = wv * 16 + rr;
        int grow = row0 + r;
        if (grow >= M) break;                    // only trims the last bucket
        int s  = rs[r];
        int e2 = s + hist[r];

        float4v acc = (float4v)(0.f);
        int base = s;
        for (; base + 8 <= e2; base += 8) {
            int2 ed[4];
#pragma unroll
            for (int u = 0; u < 4; u++) ed[u] = se[base + half + 2 * u];
            uint2 g[4];
#pragma unroll
            for (int u = 0; u < 4; u++) g[u] = sup64[(long)ed[u].x * 32 + l31];
#pragma unroll
            for (int u = 0; u < 4; u++) {
                float v = __int_as_float(ed[u].y);
                acc.x += v * __uint_as_float(g[u].x << 16);
                acc.y += v * __uint_as_float(g[u].x & 0xFFFF0000u);
                acc.z += v * __uint_as_float(g[u].y << 16);
                acc.w += v * __uint_as_float(g[u].y & 0xFFFF0000u);
            }
        }
        for (int i = base + half; i < e2; i += 2) {
            int2 ed = se[i];
            uint2 g = sup64[(long)ed.x * 32 + l31];
            float v = __int_as_float(ed.y);
            acc.x += v * __uint_as_float(g.x << 16);
            acc.y += v * __uint_as_float(g.x & 0xFFFF0000u);
            acc.z += v * __uint_as_float(g.y << 16);
            acc.w += v * __uint_as_float(g.y & 0xFFFF0000u);
        }

        // cross-half reduce: half 1's partials fold into half 0
        acc.x += __shfl_xor(acc.x, 32);
        acc.y += __shfl_xor(acc.y, 32);
        acc.z += __shfl_xor(acc.z, 32);
        acc.w += __shfl_xor(acc.w, 32);

        if (half == 0) {
            float4v o = acc + bb;
            *(float4v*)(out + (long)grow * N_FEATS + l31 * 4) = o;
        }
    }
}

extern "C" void kernel_launch(void* const* d_in, const int* in_sizes, int n_in,
                              void* d_out, int out_size, void* d_ws, size_t ws_size,
                              hipStream_t stream) {
    const float* x     = (const float*)d_in[0];
    const int*   erow  = (const int*)d_in[1];
    const int*   ecol  = (const int*)d_in[2];
    const float* eval_ = (const float*)d_in[3];
    const float* w     = (const float*)d_in[4];
    const float* b     = (const float*)d_in[5];
    float* out = (float*)d_out;

    const int M   = in_sizes[0] / K_FEATS;     // 100000
    const int E   = in_sizes[1];               // 1600000
    const int NB  = (M + BROWS - 1) >> BSHIFT; // 1563
    const int NT  = (M + 127) / 128;           // 782 gemm tiles
    const int NCH = (E + CHUNK - 1) / CHUNK;   // 196 partition chunks

    // workspace layout (16B aligned)
    size_t o_sup  = 0;                                               // bf16 sup
    size_t o_wt   = o_sup  + (((size_t)M * N_FEATS * 2 + 15) & ~15ul);
    size_t o_bcur = o_wt   + (size_t)K_FEATS * N_FEATS * 2;
    size_t o_tmp  = o_bcur + (((size_t)NB * 4 + 15) & ~15ul);

    unsigned short* sup  = (unsigned short*)((char*)d_ws + o_sup);
    unsigned short* wt   = (unsigned short*)((char*)d_ws + o_wt);
    int*            bcur = (int*)((char*)d_ws + o_bcur);
    int2*           tmp  = (int2*)((char*)d_ws + o_tmp);

    prep_w<<<N_FEATS, 256, 0, stream>>>(w, wt);
    zero_ints<<<(NB + 255) / 256, 256, 0, stream>>>(bcur, NB);

    // fused dense GEMM + sparse partition (independent until bucket_spmm)
    gemm_partition<<<NT + NCH, 256, 0, stream>>>(x, wt, sup, M, NT,
                                                 erow, ecol, eval_, bcur, tmp, E, NB, NCH);

    // sort-in-LDS + gather + out, one kernel, no global sedge
    bucket_spmm<<<NB, 256, 0, stream>>>(bcur, tmp, sup, b, out, M);
}

// Round 9
// 304.094 us; speedup vs baseline: 1.4722x; 1.0287x over previous
//
#include <hip/hip_runtime.h>

// GraphConvolution: out = segment_sum(edge_val * (x@W)[edge_col], edge_row) + b
// M=100000 nodes, K=256 in_feats, N=128 out_feats, E=1.6M edges. fp32 in/out.
//
// R9 (329.3us): barrier-free gemm fused with edge partition (mod-5 roles).
// R11 (317.5us): sort-in-LDS bucket_spmm (no global sedge), one kernel.
// R12 (312.8us): 64-row spmm buckets helped; gemm prefetch FAILED (113->124).
// R13 FAILED (NaN): B-staging index bug -- half-row is 16x16B chunks, wrote
//   n=idx>>3 (8 chunks, n to 255): OOB reads of wt + OOB LDS writes.
// R14: fix staging index (n=idx>>4, c=(idx&15)<<4). Theory stands: gemm's
//   10x gap is B-load THROUGHPUT (each wave re-read all 64KB wt at 512B
//   stride = ~200MB L1-thrashing L2 traffic). B now staged in LDS per block
//   (two 32KB halves, XOR-swizzle byte^=(n&7)<<4), inner loop reads
//   ds_read_b128. A stays direct-global. 512-thread bucket_spmm kept.

#define K_FEATS 256
#define N_FEATS 128
#define BSHIFT 7                 // 128 rows per bucket
#define BROWS 128
#define BCAP 3072                // mean 2048, +22 sigma
#define STASH 6                  // BCAP / 512
#define CHUNK 8192
#define EPT 32                   // edges per thread (256 threads)
#define RMOD 5                   // 1 of every RMOD blocks is a partition block

typedef __attribute__((ext_vector_type(8))) short short8;
typedef __attribute__((ext_vector_type(4))) float float4v;

__device__ __forceinline__ unsigned short f2bf(float f) {
    unsigned int u = __float_as_uint(f);
    unsigned int r = u + 0x7FFF + ((u >> 16) & 1);   // round-to-nearest-even
    return (unsigned short)(r >> 16);
}

// ---------------- prep: Wt[n][k] bf16 from w[k][n] fp32 ----------------
__global__ __launch_bounds__(256) void prep_w(const float* __restrict__ w,
                                              unsigned short* __restrict__ wt) {
    int n = blockIdx.x;
    int k = threadIdx.x;
    wt[n * K_FEATS + k] = f2bf(w[k * N_FEATS + n]);
}

__global__ __launch_bounds__(256) void zero_ints(int* __restrict__ p, int n) {
    int i = blockIdx.x * 256 + threadIdx.x;
    if (i < n) p[i] = 0;
}

// ---------------- fused: LDS-B GEMM + edge partition ----------------
// blockIdx % RMOD == 0 -> partition chunk; else gemm tile (128 rows).
__global__ __launch_bounds__(256) void gemm_partition(
        const float* __restrict__ x, const unsigned short* __restrict__ wt,
        unsigned short* __restrict__ sup, int M, int NT,
        const int* __restrict__ erow, const int* __restrict__ ecol,
        const float* __restrict__ eval_, int* __restrict__ bcur,
        int2* __restrict__ tmp, int E, int NB, int NCH) {
    __shared__ __align__(16) unsigned char smem[32768];
    const int g   = blockIdx.x;
    const int tid = threadIdx.x;

    if (g % RMOD == 0) {
        // ---------- partition role (8KB of smem) ----------
        int pid = g / RMOD;
        if (pid >= NCH) return;
        int* hist = (int*)smem;              // 4 KB
        int* cur  = (int*)(smem + 4096);     // 4 KB
        const long e0 = (long)pid * CHUNK;

        for (int i = tid; i < NB; i += 256) hist[i] = 0;
        __syncthreads();

        int rows[EPT];
#pragma unroll
        for (int i = 0; i < EPT; i++) {
            long e = e0 + tid + i * 256;
            int r = -1;
            if (e < E) {
                r = erow[e];
                atomicAdd(&hist[r >> BSHIFT], 1);
            }
            rows[i] = r;
        }
        __syncthreads();

        // one global reservation per touched bucket
        for (int i = tid; i < NB; i += 256) {
            int c = hist[i];
            cur[i] = c ? atomicAdd(&bcur[i], c) : 0;
        }
        __syncthreads();

        // place edges: LDS cursor gives offset within this WG's reserved run
#pragma unroll
        for (int i = 0; i < EPT; i++) {
            long e = e0 + tid + i * 256;
            if (e >= E) continue;
            int r = rows[i];
            int b = r >> BSHIFT;
            int p = atomicAdd(&cur[b], 1);
            if (p < BCAP)
                tmp[(long)b * BCAP + p] = make_int2(((r & (BROWS - 1)) << 17) | ecol[e],
                                                    __float_as_int(eval_[e]));
        }
        return;
    }

    // ---------- gemm role: B staged in LDS (swizzled), A direct global ----
    int tile = g - g / RMOD - 1;
    if (tile >= NT) return;

    unsigned char* Bs = smem;                // 32 KB: wt[n][ks*128..+128) bf16
    const int wv   = tid >> 6;
    const int lane = tid & 63;
    const int l15  = lane & 15;
    const int quad = lane >> 4;
    const int row0 = tile * 128 + wv * 32;   // this wave's 32 rows
    const int grow0 = row0 + l15;
    const int grow1 = row0 + 16 + l15;
    const bool ok0 = grow0 < M;
    const bool ok1 = grow1 < M;
    const float* p0 = x + (long)grow0 * K_FEATS + quad * 8;
    const float* p1 = x + (long)grow1 * K_FEATS + quad * 8;

    float4v acc[2][8];
#pragma unroll
    for (int mt = 0; mt < 2; mt++)
#pragma unroll
        for (int nt = 0; nt < 8; nt++) acc[mt][nt] = (float4v)(0.f);

    for (int ks = 0; ks < 2; ks++) {
        // stage half of wt: [128 n][128 k] bf16 = 32 KB, XOR-swizzled rows.
        // each half-row = 256B = 16 x 16B chunks; 2048 chunks total.
#pragma unroll
        for (int it = 0; it < 8; it++) {
            int idx = it * 256 + tid;        // 0..2047 16B-chunks
            int n   = idx >> 4;              // 0..127
            int c   = (idx & 15) << 4;       // byte 0..240 within 256B half-row
            uint4 v = *(const uint4*)((const char*)wt + (long)n * 512 + ks * 256 + c);
            int byte = (n << 8) + c;
            *(uint4*)(Bs + (byte ^ ((n & 7) << 4))) = v;
        }
        __syncthreads();

#pragma unroll
        for (int kk = 0; kk < 128; kk += 32) {
            const int k0 = ks * 128 + kk;
            // A: direct global fp32 (read-once traffic)
            float4 a00 = ok0 ? *(const float4*)(p0 + k0) : make_float4(0.f, 0.f, 0.f, 0.f);
            float4 a01 = ok0 ? *(const float4*)(p0 + k0 + 4) : make_float4(0.f, 0.f, 0.f, 0.f);
            float4 a10 = ok1 ? *(const float4*)(p1 + k0) : make_float4(0.f, 0.f, 0.f, 0.f);
            float4 a11 = ok1 ? *(const float4*)(p1 + k0 + 4) : make_float4(0.f, 0.f, 0.f, 0.f);

            // B: swizzled LDS reads (spread across 8 16B slots per 8 rows)
            short8 bfrag[8];
#pragma unroll
            for (int nt = 0; nt < 8; nt++) {
                int n    = nt * 16 + l15;
                int byte = (n << 8) + (kk << 1) + (quad << 4);
                bfrag[nt] = *(const short8*)(Bs + (byte ^ ((n & 7) << 4)));
            }

            short8 afrag[2];
            {
                short8 af;
                af[0] = (short)f2bf(a00.x); af[1] = (short)f2bf(a00.y);
                af[2] = (short)f2bf(a00.z); af[3] = (short)f2bf(a00.w);
                af[4] = (short)f2bf(a01.x); af[5] = (short)f2bf(a01.y);
                af[6] = (short)f2bf(a01.z); af[7] = (short)f2bf(a01.w);
                afrag[0] = af;
                af[0] = (short)f2bf(a10.x); af[1] = (short)f2bf(a10.y);
                af[2] = (short)f2bf(a10.z); af[3] = (short)f2bf(a10.w);
                af[4] = (short)f2bf(a11.x); af[5] = (short)f2bf(a11.y);
                af[6] = (short)f2bf(a11.z); af[7] = (short)f2bf(a11.w);
                afrag[1] = af;
            }
#pragma unroll
            for (int mt = 0; mt < 2; mt++)
#pragma unroll
                for (int nt = 0; nt < 8; nt++)
                    acc[mt][nt] = __builtin_amdgcn_mfma_f32_16x16x32_bf16(
                        afrag[mt], bfrag[nt], acc[mt][nt], 0, 0, 0);
        }
        __syncthreads();
    }

#pragma unroll
    for (int mt = 0; mt < 2; mt++) {
#pragma unroll
        for (int reg = 0; reg < 4; reg++) {
            int grow = row0 + mt * 16 + quad * 4 + reg;
            if (grow < M) {
#pragma unroll
                for (int nt = 0; nt < 8; nt++) {
                    sup[(long)grow * N_FEATS + nt * 16 + l15] = f2bf(acc[mt][nt][reg]);
                }
            }
        }
    }
}

// ---------------- fused sort+spmm: 512 threads per 128-row bucket -----------
// Phase A: tmp edges -> register stash + LDS hist; 128-scan; place into LDS
// sorted array. Phase B: wave per 16 rows, split-wave gather (8 in flight).
__global__ __launch_bounds__(512) void bucket_spmm(const int* __restrict__ bcnt,
                                                   const int2* __restrict__ tmp,
                                                   const unsigned short* __restrict__ sup,
                                                   const float* __restrict__ b,
                                                   float* __restrict__ out, int M) {
    __shared__ int hist[BROWS];
    __shared__ int rs[BROWS];
    __shared__ int cur[BROWS];
    __shared__ __align__(16) int2 se[BCAP];      // 24 KB
    const int bkt  = blockIdx.x;
    const int tid  = threadIdx.x;
    const int wv   = tid >> 6;
    const int lane = tid & 63;
    const int row0 = bkt << BSHIFT;

    if (tid < BROWS) hist[tid] = 0;
    __syncthreads();

    int cnt = bcnt[bkt];
    if (cnt > BCAP) cnt = BCAP;
    const int2* t = tmp + (long)bkt * BCAP;

    // Phase A1: single global read of bucket edges -> stash + histogram
    int2 stash[STASH];
#pragma unroll
    for (int j = 0; j < STASH; j++) {
        int i = tid + j * 512;
        if (i < cnt) {
            int2 e = t[i];
            stash[j] = e;
            atomicAdd(&hist[(unsigned)e.x >> 17], 1);
        }
    }
    __syncthreads();

    // Phase A2: exclusive scan of 128 row counts
    if (tid < BROWS) cur[tid] = hist[tid];
    __syncthreads();
#pragma unroll
    for (int s = 1; s < BROWS; s <<= 1) {
        int v = 0;
        if (tid >= s && tid < BROWS) v = cur[tid - s];
        __syncthreads();
        if (tid < BROWS) cur[tid] += v;
        __syncthreads();
    }
    if (tid < BROWS) {
        int start = cur[tid] - hist[tid];        // exclusive
        rs[tid]  = start;
        cur[tid] = start;
    }
    __syncthreads();

    // Phase A3: place edges into LDS sorted array (col stripped of row bits)
#pragma unroll
    for (int j = 0; j < STASH; j++) {
        int i = tid + j * 512;
        if (i < cnt) {
            int2 e = stash[j];
            int rl = (unsigned)e.x >> 17;
            int p = atomicAdd(&cur[rl], 1);
            se[p] = make_int2(e.x & 0x1FFFF, e.y);
        }
    }
    __syncthreads();

    // Phase B: wave per 16 rows, split-wave gather (8 in flight)
    const int half = lane >> 5;
    const int l31  = lane & 31;
    const uint2* sup64 = (const uint2*)sup;      // 4 bf16 per uint2
    const float4v bb = ((const float4v*)b)[l31];

    for (int rr = 0; rr < 16; rr++) {
        int r    = wv * 16 + rr;
        int grow = row0 + r;
        if (grow >= M) break;                    // only trims the last bucket
        int s  = rs[r];
        int e2 = s + hist[r];

        float4v acc = (float4v)(0.f);
        int base = s;
        for (; base + 8 <= e2; base += 8) {
            int2 ed[4];
#pragma unroll
            for (int u = 0; u < 4; u++) ed[u] = se[base + half + 2 * u];
            uint2 g[4];
#pragma unroll
            for (int u = 0; u < 4; u++) g[u] = sup64[(long)ed[u].x * 32 + l31];
#pragma unroll
            for (int u = 0; u < 4; u++) {
                float v = __int_as_float(ed[u].y);
                acc.x += v * __uint_as_float(g[u].x << 16);
                acc.y += v * __uint_as_float(g[u].x & 0xFFFF0000u);
                acc.z += v * __uint_as_float(g[u].y << 16);
                acc.w += v * __uint_as_float(g[u].y & 0xFFFF0000u);
            }
        }
        for (int i = base + half; i < e2; i += 2) {
            int2 ed = se[i];
            uint2 g = sup64[(long)ed.x * 32 + l31];
            float v = __int_as_float(ed.y);
            acc.x += v * __uint_as_float(g.x << 16);
            acc.y += v * __uint_as_float(g.x & 0xFFFF0000u);
            acc.z += v * __uint_as_float(g.y << 16);
            acc.w += v * __uint_as_float(g.y & 0xFFFF0000u);
        }

        // cross-half reduce: half 1's partials fold into half 0
        acc.x += __shfl_xor(acc.x, 32);
        acc.y += __shfl_xor(acc.y, 32);
        acc.z += __shfl_xor(acc.z, 32);
        acc.w += __shfl_xor(acc.w, 32);

        if (half == 0) {
            float4v o = acc + bb;
            *(float4v*)(out + (long)grow * N_FEATS + l31 * 4) = o;
        }
    }
}

extern "C" void kernel_launch(void* const* d_in, const int* in_sizes, int n_in,
                              void* d_out, int out_size, void* d_ws, size_t ws_size,
                              hipStream_t stream) {
    const float* x     = (const float*)d_in[0];
    const int*   erow  = (const int*)d_in[1];
    const int*   ecol  = (const int*)d_in[2];
    const float* eval_ = (const float*)d_in[3];
    const float* w     = (const float*)d_in[4];
    const float* b     = (const float*)d_in[5];
    float* out = (float*)d_out;

    const int M   = in_sizes[0] / K_FEATS;     // 100000
    const int E   = in_sizes[1];               // 1600000
    const int NB  = (M + BROWS - 1) >> BSHIFT; // 782
    const int NT  = (M + 127) / 128;           // 782 gemm tiles
    const int NCH = (E + CHUNK - 1) / CHUNK;   // 196 partition chunks

    // workspace layout (16B aligned)
    size_t o_sup  = 0;                                               // bf16 sup
    size_t o_wt   = o_sup  + (((size_t)M * N_FEATS * 2 + 15) & ~15ul);
    size_t o_bcur = o_wt   + (size_t)K_FEATS * N_FEATS * 2;
    size_t o_tmp  = o_bcur + (((size_t)NB * 4 + 15) & ~15ul);

    unsigned short* sup  = (unsigned short*)((char*)d_ws + o_sup);
    unsigned short* wt   = (unsigned short*)((char*)d_ws + o_wt);
    int*            bcur = (int*)((char*)d_ws + o_bcur);
    int2*           tmp  = (int2*)((char*)d_ws + o_tmp);

    prep_w<<<N_FEATS, 256, 0, stream>>>(w, wt);
    zero_ints<<<(NB + 255) / 256, 256, 0, stream>>>(bcur, NB);

    // fused dense GEMM (B in LDS) + sparse partition
    gemm_partition<<<NT + NCH, 256, 0, stream>>>(x, wt, sup, M, NT,
                                                 erow, ecol, eval_, bcur, tmp, E, NB, NCH);

    // sort-in-LDS + gather + out, one kernel, no global sedge
    bucket_spmm<<<NB, 512, 0, stream>>>(bcur, tmp, sup, b, out, M);
}